// Round 1
// baseline (620.651 us; speedup 1.0000x reference)
//
#include <hip/hip_runtime.h>

// MLPPredictor: score[e] = relu(h[src[e]]@W1u + h[dst[e]]@W1v + b1) @ W2 + b2
// Key algebraic factorization: first layer is linear per-node -> precompute
// PQ = h @ [W1u|W1v]  (100000 x 256, bf16, in d_ws) once, then per-edge work
// is gather + add + relu + (1M x 128) @ (128 x 86) MFMA GEMM.

typedef short bf16x8 __attribute__((ext_vector_type(8)));   // 8 bf16 = 4 VGPR
typedef float f32x4 __attribute__((ext_vector_type(4)));

#define DIM 128
#define C_OUT 86
#define NPAD 96      // 86 padded to 6 x 16 MFMA tiles
#define HSTRIDE 136  // bf16 row stride for LDS fragments (=8-pad: conflict-free b128)

__device__ __forceinline__ float bf2f(unsigned short u) {
    unsigned int x = ((unsigned int)u) << 16;
    float f;
    __builtin_memcpy(&f, &x, 4);
    return f;
}
__device__ __forceinline__ unsigned short f2bf(float f) {
    unsigned int x;
    __builtin_memcpy(&x, &f, 4);
    x = x + 0x7fffu + ((x >> 16) & 1u);   // round-to-nearest-even
    return (unsigned short)(x >> 16);
}

// ---------------- Stage A: PQ[n][0:128]=h[n]@W1u, PQ[n][128:256]=h[n]@W1v ----
// fp32 vector GEMM, M=n_nodes N=256 K=128, 64x64 tile, 4x4 register block.
__global__ __launch_bounds__(256) void node_gemm_kernel(
    const float* __restrict__ h, const float* __restrict__ W1,
    unsigned short* __restrict__ PQ, int n_nodes)
{
    __shared__ float As[64][33];   // +1 pad breaks row-stride bank aliasing
    __shared__ float Bs[32][64];
    const int t = threadIdx.x;
    const int m0 = blockIdx.x * 64;
    const int n0 = blockIdx.y * 64;   // 0,64 -> W1u cols; 128,192 -> W1v cols
    const float* Bbase = (n0 < 128) ? (W1 + n0) : (W1 + 128 * 128 + (n0 - 128));
    const int tx = t & 15, ty = t >> 4;
    float acc[4][4] = {};
    for (int k0 = 0; k0 < 128; k0 += 32) {
#pragma unroll
        for (int i = 0; i < 2; ++i) {   // A tile: 64x32
            int f = t + i * 256;
            int r = f >> 3;
            int kc = (f & 7) << 2;
            int gr = m0 + r;
            float4 v = make_float4(0.f, 0.f, 0.f, 0.f);
            if (gr < n_nodes) v = *(const float4*)(h + (size_t)gr * DIM + k0 + kc);
            As[r][kc + 0] = v.x; As[r][kc + 1] = v.y;
            As[r][kc + 2] = v.z; As[r][kc + 3] = v.w;
        }
#pragma unroll
        for (int i = 0; i < 2; ++i) {   // B tile: 32x64 (W1 rows stride 128)
            int f = t + i * 256;
            int kk = f >> 4;
            int jc = (f & 15) << 2;
            *(float4*)&Bs[kk][jc] = *(const float4*)(Bbase + (size_t)(k0 + kk) * DIM + jc);
        }
        __syncthreads();
#pragma unroll
        for (int kk = 0; kk < 32; ++kk) {
            float a[4], b[4];
#pragma unroll
            for (int r = 0; r < 4; ++r) a[r] = As[ty * 4 + r][kk];
#pragma unroll
            for (int c = 0; c < 4; ++c) b[c] = Bs[kk][tx * 4 + c];
#pragma unroll
            for (int r = 0; r < 4; ++r)
#pragma unroll
                for (int c = 0; c < 4; ++c) acc[r][c] += a[r] * b[c];
        }
        __syncthreads();
    }
#pragma unroll
    for (int r = 0; r < 4; ++r) {
        int gm = m0 + ty * 4 + r;
        if (gm < n_nodes) {
            ushort4 o = make_ushort4(f2bf(acc[r][0]), f2bf(acc[r][1]),
                                     f2bf(acc[r][2]), f2bf(acc[r][3]));
            *(ushort4*)(PQ + (size_t)gm * 256 + n0 + tx * 4) = o;
        }
    }
}

// ---------------- Stage B: per-edge MLP via MFMA -----------------------------
// Per chunk of 64 edges: hid (64x128 bf16) built into LDS in A-fragment layout,
// then 4 waves x (16 edges x 96 cols) = 24 MFMAs/wave vs W2 B-frags in regs.
__global__ __launch_bounds__(256) void edge_mlp_kernel(
    const unsigned short* __restrict__ PQ,
    const float* __restrict__ b1,
    const float* __restrict__ W2,
    const float* __restrict__ b2,
    const int* __restrict__ src,
    const int* __restrict__ dst,
    float* __restrict__ out,
    int n_edges)
{
    __shared__ unsigned short W2T[NPAD * HSTRIDE];   // W2 transposed [n][k], bf16
    __shared__ unsigned short hidL[64 * HSTRIDE];    // hid rows, bf16
    __shared__ float b1s[DIM];
    __shared__ float b2s[NPAD];

    const int t = threadIdx.x;
    for (int i = t; i < NPAD * DIM; i += 256) {      // setup: W2 -> W2T (bf16)
        int n = i >> 7;
        int k = i & 127;
        float v = (n < C_OUT) ? W2[(size_t)k * C_OUT + n] : 0.f;
        W2T[n * HSTRIDE + k] = f2bf(v);
    }
    if (t < DIM) b1s[t] = b1[t];
    if (t < NPAD) b2s[t] = (t < C_OUT) ? b2[t] : 0.f;
    __syncthreads();

    const int lane = t & 63;
    const int wv = t >> 6;        // wave 0..3 -> 16-edge strip
    const int m = lane & 15;
    const int quad = lane >> 4;

    // B fragments: B[k][n], n = lane&15, k = kt*32 + quad*8 + j  (held in regs)
    bf16x8 Bfrag[6][4];
#pragma unroll
    for (int nt = 0; nt < 6; ++nt)
#pragma unroll
        for (int kt = 0; kt < 4; ++kt)
            Bfrag[nt][kt] = *(const bf16x8*)&W2T[(nt * 16 + m) * HSTRIDE + kt * 32 + quad * 8];

    const ushort4* PQ4 = (const ushort4*)PQ;   // node row = 64 ushort4 (P:0..31, Q:32..63)

    for (int e0 = blockIdx.x * 64; e0 < n_edges; e0 += gridDim.x * 64) {
        // phase 1: hid[e][k] = relu(P[src][k] + Q[dst][k] + b1[k]) -> bf16 LDS
#pragma unroll
        for (int i = 0; i < 8; ++i) {
            int qi = t + i * 256;     // 0..2047 quads
            int e = qi >> 5;
            int q = qi & 31;
            int edge = e0 + e;
            ushort4 hv = make_ushort4(0, 0, 0, 0);
            if (edge < n_edges) {
                int s = src[edge];
                int d = dst[edge];
                ushort4 pv = PQ4[(size_t)s * 64 + q];
                ushort4 qv = PQ4[(size_t)d * 64 + 32 + q];
                int k = q << 2;
                float4 bb = *(const float4*)&b1s[k];
                float x0 = fmaxf(bf2f(pv.x) + bf2f(qv.x) + bb.x, 0.f);
                float x1 = fmaxf(bf2f(pv.y) + bf2f(qv.y) + bb.y, 0.f);
                float x2 = fmaxf(bf2f(pv.z) + bf2f(qv.z) + bb.z, 0.f);
                float x3 = fmaxf(bf2f(pv.w) + bf2f(qv.w) + bb.w, 0.f);
                hv = make_ushort4(f2bf(x0), f2bf(x1), f2bf(x2), f2bf(x3));
            }
            *(ushort4*)&hidL[e * HSTRIDE + (q << 2)] = hv;
        }
        __syncthreads();

        // phase 2: 16x96 per wave, K=128 in 4 MFMA steps
        bf16x8 af[4];
#pragma unroll
        for (int kt = 0; kt < 4; ++kt)
            af[kt] = *(const bf16x8*)&hidL[(wv * 16 + m) * HSTRIDE + kt * 32 + quad * 8];

#pragma unroll
        for (int nt = 0; nt < 6; ++nt) {
            f32x4 acc = {0.f, 0.f, 0.f, 0.f};
#pragma unroll
            for (int kt = 0; kt < 4; ++kt)
                acc = __builtin_amdgcn_mfma_f32_16x16x32_bf16(af[kt], Bfrag[nt][kt], acc, 0, 0, 0);
            int col = nt * 16 + m;   // C/D: col = lane&15, row = quad*4 + reg
            if (col < C_OUT) {
                float bias = b2s[col];
                int ebase = e0 + wv * 16 + quad * 4;
#pragma unroll
                for (int r = 0; r < 4; ++r) {
                    int edge = ebase + r;
                    if (edge < n_edges)
                        out[(size_t)edge * C_OUT + col] = acc[r] + bias;
                }
            }
        }
        __syncthreads();   // protect hidL before next chunk overwrites
    }
}

extern "C" void kernel_launch(void* const* d_in, const int* in_sizes, int n_in,
                              void* d_out, int out_size, void* d_ws, size_t ws_size,
                              hipStream_t stream) {
    const float* h  = (const float*)d_in[0];
    const float* W1 = (const float*)d_in[1];
    const float* b1 = (const float*)d_in[2];
    const float* W2 = (const float*)d_in[3];
    const float* b2 = (const float*)d_in[4];
    const int* src  = (const int*)d_in[5];
    const int* dst  = (const int*)d_in[6];
    float* out = (float*)d_out;
    const int n_nodes = in_sizes[0] / DIM;      // 100000
    const int n_edges = in_sizes[5];            // 1000000
    unsigned short* PQ = (unsigned short*)d_ws; // 100000*256 bf16 = 51.2 MB

    node_gemm_kernel<<<dim3((n_nodes + 63) / 64, 4), 256, 0, stream>>>(h, W1, PQ, n_nodes);
    edge_mlp_kernel<<<dim3(768), 256, 0, stream>>>(PQ, b1, W2, b2, src, dst, out, n_edges);
}